// Round 6
// baseline (106.583 us; speedup 1.0000x reference)
//
#include <hip/hip_runtime.h>

#define HW       262144      // 512*512 elements per image plane
#define NBINS    10
#define NBLOCKS  2048

// d_ws layout (floats):
//   [q*32 + slot], q in [0,10)  : cumulative count C[k] (C[0] == valid total)
//   [q*32 + slot], q in [10,20) : cumulative weighted-log sum S[k]
//   [672] (byte 2688)           : completion counter (u32)
// Clear must COVER the counter: 4096 bytes > 673*4.
#define WS_CLEAR_BYTES 4096

__global__ __launch_bounds__(256, 8) void ghm_fused(
    const float* __restrict__ pred, const float* __restrict__ target,
    float* __restrict__ ws, float* __restrict__ out)
{
    __shared__ float shred[4][32];
    __shared__ float qsh[20];

    const int tid  = threadIdx.x;
    const int lane = tid & 63;
    const int wv   = tid >> 6;

    // 2048 blocks: 64 tiles of 1024 vec4s per image, 32 images
    const int img = blockIdx.x >> 6;
    const int v0  = (blockIdx.x & 63) * 1024 + tid;

    const float* pp = pred   + (size_t)img * HW;
    const float* th = target + (size_t)img * (3 * HW);

    float4 p4[4], hm4[4], vl4[4], ps4[4];
    #pragma unroll
    for (int k = 0; k < 4; ++k) {
        const int r = (v0 + (k << 8)) << 2;
        p4[k]  = *reinterpret_cast<const float4*>(pp + r);
        hm4[k] = *reinterpret_cast<const float4*>(th + r);
        vl4[k] = *reinterpret_cast<const float4*>(th + HW + r);
        ps4[k] = *reinterpret_cast<const float4*>(th + 2 * HW + r);
    }

    float ck[NBINS], sk[NBINS];
    #pragma unroll
    for (int b = 0; b < NBINS; ++b) { ck[b] = 0.f; sk[b] = 0.f; }

    #pragma unroll
    for (int k = 0; k < 4; ++k) {
        #pragma unroll
        for (int j = 0; j < 4; ++j) {
            const float p  = (&p4[k].x)[j];
            const float hm = (&hm4[k].x)[j];
            const float vl = (&vl4[k].x)[j];   // 0.0 or 1.0
            const float ps = (&ps4[k].x)[j];   // 0.0 or 1.0, ps <= vl

            // p in (1e-4, 1-1e-4) => g = |p*vl - ps| < 1 strictly, so
            // in_bin == valid == (vl > 0); count-of-valid == tot.
            const float g  = fabsf(__builtin_fmaf(p, vl, -ps));
            const bool isP = (ps != 0.f);

            const float x  = isP ? p : 1.f - p;
            const float l  = __logf(x);
            const float t  = 1.f - hm;
            const float t2 = t * t;
            const float nw = t2 * t2;                    // (1-hm)^4
            const float lfac = vl * (isP ? l : l * nw);  // masked by valid

            ck[0] += vl;
            sk[0] += lfac;
            #pragma unroll
            for (int b = 1; b < NBINS; ++b) {
                const float edge = (b == 1) ? 0.1f : (b == 2) ? 0.2f :
                                   (b == 3) ? 0.3f : (b == 4) ? 0.4f :
                                   (b == 5) ? 0.5f : (b == 6) ? 0.6f :
                                   (b == 7) ? 0.7f : (b == 8) ? 0.8f : 0.9f;
                const float sel = (g >= edge) ? 1.f : 0.f;
                ck[b] = __builtin_fmaf(sel, vl,   ck[b]);
                sk[b] = __builtin_fmaf(sel, lfac, sk[b]);
            }
        }
    }

    // 64-lane butterfly reduce of the 20 register accumulators
    #pragma unroll
    for (int off = 32; off; off >>= 1) {
        #pragma unroll
        for (int b = 0; b < NBINS; ++b) {
            ck[b] += __shfl_xor(ck[b], off);
            sk[b] += __shfl_xor(sk[b], off);
        }
    }

    if (lane == 0) {
        #pragma unroll
        for (int b = 0; b < NBINS; ++b) {
            shred[wv][b]      = ck[b];
            shred[wv][10 + b] = sk[b];
        }
    }
    __syncthreads();

    const int slot = blockIdx.x & 31;
    if (tid < 20) {
        const float s = shred[0][tid] + shred[1][tid] +
                        shred[2][tid] + shred[3][tid];
        atomicAdd(&ws[tid * 32 + slot], s);
    }
    __syncthreads();                       // drains wave-0's atomics (vmcnt 0)

    // ---- last-block finalize ----
    unsigned int* cnt = (unsigned int*)(ws + 672);
    __shared__ unsigned int isLast;
    if (tid == 0) {
        __threadfence();                   // release our partials
        isLast = (atomicAdd(cnt, 1u) == NBLOCKS - 1) ? 1u : 0u;
    }
    __syncthreads();
    if (!isLast) return;

    if (tid < 20) {
        float s = 0.f;
        #pragma unroll
        for (int j = 0; j < 32; ++j)
            s += atomicAdd(&ws[tid * 32 + j], 0.f);   // coherent read-back
        qsh[tid] = s;
    }
    __syncthreads();

    if (tid == 0) {
        float tot = qsh[0];                // C[0] == valid count
        if (tot < 1.f) tot = 1.f;

        float cnt_b[NBINS], sv[NBINS];
        for (int b = 0; b < NBINS - 1; ++b) {
            cnt_b[b] = qsh[b]      - qsh[b + 1];
            sv[b]    = qsh[10 + b] - qsh[11 + b];
        }
        cnt_b[NBINS - 1] = qsh[NBINS - 1];
        sv[NBINS - 1]    = qsh[19];

        int nne = 0;
        for (int b = 0; b < NBINS; ++b) if (cnt_b[b] > 0.f) nne++;
        const float nn = (nne > 0) ? (float)nne : 1.f;

        float s = 0.f;
        for (int b = 0; b < NBINS; ++b) {
            const float w = (cnt_b[b] > 0.f) ? (tot / fmaxf(cnt_b[b], 1.f)) / nn
                                             : 0.f;
            s += sv[b] * w;
        }
        out[0] = -s / tot;
    }
}

extern "C" void kernel_launch(void* const* d_in, const int* in_sizes, int n_in,
                              void* d_out, int out_size, void* d_ws, size_t ws_size,
                              hipStream_t stream)
{
    const float* pred   = (const float*)d_in[0];
    const float* target = (const float*)d_in[1];
    float*       out    = (float*)d_out;
    float*       ws     = (float*)d_ws;

    hipMemsetAsync(d_ws, 0, WS_CLEAR_BYTES, stream);
    ghm_fused<<<NBLOCKS, 256, 0, stream>>>(pred, target, ws, out);
}

// Round 7
// 93.733 us; speedup vs baseline: 1.1371x; 1.1371x over previous
//
#include <hip/hip_runtime.h>

#define HW       262144      // 512*512 elements per image plane
#define NBINS    10
#define NBLOCKS  2048

// d_ws layout (floats):
//   [q*32 + slot], q in [0,10)  : cumulative count C[k] (C[0] == valid total)
//   [q*32 + slot], q in [10,20) : cumulative weighted-log sum S[k]
//   [672] (byte 2688)           : completion counter (u32)
// Clear must COVER the counter: 4096 bytes > 673*4.
#define WS_CLEAR_BYTES 4096

__global__ __launch_bounds__(256) void ghm_fused(
    const float* __restrict__ pred, const float* __restrict__ target,
    float* __restrict__ ws, float* __restrict__ out)
{
    __shared__ float shred[4][32];
    __shared__ float qsh[20];

    const int tid  = threadIdx.x;
    const int lane = tid & 63;
    const int wv   = tid >> 6;

    // 2048 blocks: 64 tiles of 1024 vec4s per image, 32 images
    const int img = blockIdx.x >> 6;
    const int v0  = (blockIdx.x & 63) * 1024 + tid;

    const float* pp = pred   + (size_t)img * HW;
    const float* th = target + (size_t)img * (3 * HW);

    float4 p4[4], hm4[4], vl4[4], ps4[4];
    #pragma unroll
    for (int k = 0; k < 4; ++k) {
        const int r = (v0 + (k << 8)) << 2;
        p4[k]  = *reinterpret_cast<const float4*>(pp + r);
        hm4[k] = *reinterpret_cast<const float4*>(th + r);
        vl4[k] = *reinterpret_cast<const float4*>(th + HW + r);
        ps4[k] = *reinterpret_cast<const float4*>(th + 2 * HW + r);
    }

    float ck[NBINS], sk[NBINS];
    #pragma unroll
    for (int b = 0; b < NBINS; ++b) { ck[b] = 0.f; sk[b] = 0.f; }

    #pragma unroll
    for (int k = 0; k < 4; ++k) {
        #pragma unroll
        for (int j = 0; j < 4; ++j) {
            const float p  = (&p4[k].x)[j];
            const float hm = (&hm4[k].x)[j];
            const float vl = (&vl4[k].x)[j];   // 0.0 or 1.0
            const float ps = (&ps4[k].x)[j];   // 0.0 or 1.0, ps <= vl

            // p in (1e-4, 1-1e-4) => g = |p*vl - ps| < 1 strictly, so
            // in_bin == valid == (vl > 0); count-of-valid == tot.
            const float g  = fabsf(__builtin_fmaf(p, vl, -ps));
            const bool isP = (ps != 0.f);

            const float x  = isP ? p : 1.f - p;
            const float l  = __logf(x);
            const float t  = 1.f - hm;
            const float t2 = t * t;
            const float nw = t2 * t2;                    // (1-hm)^4
            const float lfac = vl * (isP ? l : l * nw);  // masked by valid

            ck[0] += vl;
            sk[0] += lfac;
            #pragma unroll
            for (int b = 1; b < NBINS; ++b) {
                const float edge = (b == 1) ? 0.1f : (b == 2) ? 0.2f :
                                   (b == 3) ? 0.3f : (b == 4) ? 0.4f :
                                   (b == 5) ? 0.5f : (b == 6) ? 0.6f :
                                   (b == 7) ? 0.7f : (b == 8) ? 0.8f : 0.9f;
                const float sel = (g >= edge) ? 1.f : 0.f;
                ck[b] = __builtin_fmaf(sel, vl,   ck[b]);
                sk[b] = __builtin_fmaf(sel, lfac, sk[b]);
            }
        }
    }

    // 64-lane butterfly reduce of the 20 register accumulators
    #pragma unroll
    for (int off = 32; off; off >>= 1) {
        #pragma unroll
        for (int b = 0; b < NBINS; ++b) {
            ck[b] += __shfl_xor(ck[b], off);
            sk[b] += __shfl_xor(sk[b], off);
        }
    }

    if (lane == 0) {
        #pragma unroll
        for (int b = 0; b < NBINS; ++b) {
            shred[wv][b]      = ck[b];
            shred[wv][10 + b] = sk[b];
        }
    }
    __syncthreads();

    const int slot = blockIdx.x & 31;
    if (tid < 20) {
        const float s = shred[0][tid] + shred[1][tid] +
                        shred[2][tid] + shred[3][tid];
        atomicAdd(&ws[tid * 32 + slot], s);
    }
    __syncthreads();

    // ---- last-block finalize ----
    unsigned int* cnt = (unsigned int*)(ws + 672);
    __shared__ unsigned int isLast;
    if (tid == 0) {
        __threadfence();                   // release our partials
        isLast = (atomicAdd(cnt, 1u) == NBLOCKS - 1) ? 1u : 0u;
    }
    __syncthreads();
    if (!isLast) return;

    if (tid < 20) {
        float s = 0.f;
        #pragma unroll
        for (int j = 0; j < 32; ++j)
            s += atomicAdd(&ws[tid * 32 + j], 0.f);   // coherent read-back
        qsh[tid] = s;
    }
    __syncthreads();

    if (tid == 0) {
        float tot = qsh[0];                // C[0] == valid count
        if (tot < 1.f) tot = 1.f;

        float cnt_b[NBINS], sv[NBINS];
        for (int b = 0; b < NBINS - 1; ++b) {
            cnt_b[b] = qsh[b]      - qsh[b + 1];
            sv[b]    = qsh[10 + b] - qsh[11 + b];
        }
        cnt_b[NBINS - 1] = qsh[NBINS - 1];
        sv[NBINS - 1]    = qsh[19];

        int nne = 0;
        for (int b = 0; b < NBINS; ++b) if (cnt_b[b] > 0.f) nne++;
        const float nn = (nne > 0) ? (float)nne : 1.f;

        float s = 0.f;
        for (int b = 0; b < NBINS; ++b) {
            const float w = (cnt_b[b] > 0.f) ? (tot / fmaxf(cnt_b[b], 1.f)) / nn
                                             : 0.f;
            s += sv[b] * w;
        }
        out[0] = -s / tot;
    }
}

extern "C" void kernel_launch(void* const* d_in, const int* in_sizes, int n_in,
                              void* d_out, int out_size, void* d_ws, size_t ws_size,
                              hipStream_t stream)
{
    const float* pred   = (const float*)d_in[0];
    const float* target = (const float*)d_in[1];
    float*       out    = (float*)d_out;
    float*       ws     = (float*)d_ws;

    hipMemsetAsync(d_ws, 0, WS_CLEAR_BYTES, stream);
    ghm_fused<<<NBLOCKS, 256, 0, stream>>>(pred, target, ws, out);
}

// Round 8
// 50.236 us; speedup vs baseline: 2.1216x; 1.8658x over previous
//
#include <hip/hip_runtime.h>

#define HW       262144      // 512*512 elements per image plane
#define NBINS    10

// d_ws: 20 cumulative quantities * 32 replica slots (fp32):
//   q in [0,10)  : C[k] = count of (valid & g >= k/10); C[0] == valid total
//   q in [10,20) : S[k] = sum of weighted-log where g >= k/10
#define WS_FLOATS (20 * 32)

__global__ __launch_bounds__(256) void ghm_accum(
    const float* __restrict__ pred, const float* __restrict__ target,
    float* __restrict__ ws)
{
    __shared__ float shred[4][32];

    const int tid  = threadIdx.x;
    const int lane = tid & 63;
    const int wv   = tid >> 6;

    // 2048 blocks: 64 tiles of 1024 vec4s per image, 32 images
    const int img = blockIdx.x >> 6;
    const int v0  = (blockIdx.x & 63) * 1024 + tid;

    const float* pp = pred   + (size_t)img * HW;
    const float* th = target + (size_t)img * (3 * HW);

    // ---- phase 1: issue ALL 16 loads (256 B/thread in flight) ----
    float4 p4[4], hm4[4], vl4[4], ps4[4];
    #pragma unroll
    for (int k = 0; k < 4; ++k) {
        const int r = (v0 + (k << 8)) << 2;
        p4[k]  = *reinterpret_cast<const float4*>(pp + r);
        hm4[k] = *reinterpret_cast<const float4*>(th + r);
        vl4[k] = *reinterpret_cast<const float4*>(th + HW + r);
        ps4[k] = *reinterpret_cast<const float4*>(th + 2 * HW + r);
    }
    // hard scheduling fence: loads may not sink below, uses may not hoist above
    __builtin_amdgcn_sched_barrier(0);

    // ---- phase 2: compute (registers only) ----
    float ck[NBINS], sk[NBINS];
    #pragma unroll
    for (int b = 0; b < NBINS; ++b) { ck[b] = 0.f; sk[b] = 0.f; }

    #pragma unroll
    for (int k = 0; k < 4; ++k) {
        #pragma unroll
        for (int j = 0; j < 4; ++j) {
            const float p  = (&p4[k].x)[j];
            const float hm = (&hm4[k].x)[j];
            const float vl = (&vl4[k].x)[j];   // 0.0 or 1.0
            const float ps = (&ps4[k].x)[j];   // 0.0 or 1.0, ps <= vl

            // p in (1e-4, 1-1e-4) => g = |p*vl - ps| < 1 strictly, so
            // in_bin == valid == (vl > 0); count-of-valid == tot.
            const float g  = fabsf(__builtin_fmaf(p, vl, -ps));
            const bool isP = (ps != 0.f);

            const float x  = isP ? p : 1.f - p;
            const float l  = __logf(x);
            const float t  = 1.f - hm;
            const float t2 = t * t;
            const float nw = t2 * t2;                    // (1-hm)^4
            const float lfac = vl * (isP ? l : l * nw);  // masked by valid

            ck[0] += vl;
            sk[0] += lfac;
            #pragma unroll
            for (int b = 1; b < NBINS; ++b) {
                const float edge = (b == 1) ? 0.1f : (b == 2) ? 0.2f :
                                   (b == 3) ? 0.3f : (b == 4) ? 0.4f :
                                   (b == 5) ? 0.5f : (b == 6) ? 0.6f :
                                   (b == 7) ? 0.7f : (b == 8) ? 0.8f : 0.9f;
                const float sel = (g >= edge) ? 1.f : 0.f;
                ck[b] = __builtin_fmaf(sel, vl,   ck[b]);
                sk[b] = __builtin_fmaf(sel, lfac, sk[b]);
            }
        }
    }

    // 64-lane butterfly reduce of the 20 register accumulators
    #pragma unroll
    for (int off = 32; off; off >>= 1) {
        #pragma unroll
        for (int b = 0; b < NBINS; ++b) {
            ck[b] += __shfl_xor(ck[b], off);
            sk[b] += __shfl_xor(sk[b], off);
        }
    }

    if (lane == 0) {
        #pragma unroll
        for (int b = 0; b < NBINS; ++b) {
            shred[wv][b]      = ck[b];
            shred[wv][10 + b] = sk[b];
        }
    }
    __syncthreads();

    if (tid < 20) {
        const float s = shred[0][tid] + shred[1][tid] +
                        shred[2][tid] + shred[3][tid];
        atomicAdd(&ws[tid * 32 + (blockIdx.x & 31)], s);
    }
}

__global__ void ghm_final(const float* __restrict__ ws, float* __restrict__ out)
{
    __shared__ float q[20];
    const int tid = threadIdx.x;
    if (tid < 20) {
        float s = 0.f;
        #pragma unroll
        for (int j = 0; j < 32; ++j) s += ws[tid * 32 + j];
        q[tid] = s;
    }
    __syncthreads();

    if (tid == 0) {
        float tot = q[0];                  // C[0] == valid count
        if (tot < 1.f) tot = 1.f;

        float cnt_b[NBINS], sv[NBINS];
        for (int b = 0; b < NBINS - 1; ++b) {
            cnt_b[b] = q[b]      - q[b + 1];
            sv[b]    = q[10 + b] - q[11 + b];
        }
        cnt_b[NBINS - 1] = q[NBINS - 1];
        sv[NBINS - 1]    = q[19];

        int nne = 0;
        for (int b = 0; b < NBINS; ++b) if (cnt_b[b] > 0.f) nne++;
        const float nn = (nne > 0) ? (float)nne : 1.f;

        float s = 0.f;
        for (int b = 0; b < NBINS; ++b) {
            const float w = (cnt_b[b] > 0.f) ? (tot / fmaxf(cnt_b[b], 1.f)) / nn
                                             : 0.f;
            s += sv[b] * w;
        }
        out[0] = -s / tot;
    }
}

extern "C" void kernel_launch(void* const* d_in, const int* in_sizes, int n_in,
                              void* d_out, int out_size, void* d_ws, size_t ws_size,
                              hipStream_t stream)
{
    const float* pred   = (const float*)d_in[0];
    const float* target = (const float*)d_in[1];
    float*       out    = (float*)d_out;
    float*       ws     = (float*)d_ws;

    hipMemsetAsync(d_ws, 0, WS_FLOATS * sizeof(float), stream);
    ghm_accum<<<2048, 256, 0, stream>>>(pred, target, ws);
    ghm_final<<<1, 64, 0, stream>>>(ws, out);
}